// Round 13
// baseline (171.983 us; speedup 1.0000x reference)
//
#include <hip/hip_runtime.h>
#include <hip/hip_bf16.h>
#include <cstdint>

#define CH 2048
#define NCF 8192          // 4 * CH
#define NJ 24             // 4 pre + 4 post + 16 res
#define RPB 4             // batch rows per block (K1)
#define EPS_F 1e-5f
#define SINK_ITERS 20

typedef float v4f __attribute__((ext_vector_type(4)));

__device__ __forceinline__ uint32_t bf16rne(float f) {
    uint32_t u = __float_as_uint(f);
    return (u + 0x7fffu + ((u >> 16) & 1u)) >> 16;
}

// pack 2 f32 -> 2 bf16 in one instruction (lo -> [15:0], hi -> [31:16])
__device__ __forceinline__ uint32_t cvtpk(float lo, float hi) {
    uint32_t r;
    asm("v_cvt_pk_bf16_f32 %0, %1, %2" : "=v"(r) : "v"(lo), "v"(hi));
    return r;
}

// dot of 8 bf16 pairs (packed in uint4) via v_dot2_f32_bf16
__device__ __forceinline__ float dot8(const uint4& x, const uint4& p, float acc) {
    asm("v_dot2_f32_bf16 %0, %1, %2, %0" : "+v"(acc) : "v"(x.x), "v"(p.x));
    asm("v_dot2_f32_bf16 %0, %1, %2, %0" : "+v"(acc) : "v"(x.y), "v"(p.y));
    asm("v_dot2_f32_bf16 %0, %1, %2, %0" : "+v"(acc) : "v"(x.z), "v"(p.z));
    asm("v_dot2_f32_bf16 %0, %1, %2, %0" : "+v"(acc) : "v"(x.w), "v"(p.w));
    return acc;
}

// ---------------------------------------------------------------------------
// Prep: phiW[j][k] = bf16( alpha_j * w[k % CH] * phi_j[k] ),  j in [0,24)
// ---------------------------------------------------------------------------
__global__ void __launch_bounds__(256) prep_phi_kernel(
    const float* __restrict__ w,
    const float* __restrict__ phi_pre,
    const float* __restrict__ phi_post,
    const float* __restrict__ phi_res,
    const float* __restrict__ alpha_pre,
    const float* __restrict__ alpha_post,
    const float* __restrict__ alpha_res,
    uint16_t* __restrict__ phiW)
{
    int idx = blockIdx.x * 256 + threadIdx.x;
    if (idx >= NJ * NCF) return;
    int j = idx / NCF;
    int k = idx - j * NCF;
    int c = k & (CH - 1);
    float v, a;
    if (j < 4)      { v = phi_pre[j * NCF + k];        a = alpha_pre[0]; }
    else if (j < 8) { v = phi_post[(j - 4) * NCF + k]; a = alpha_post[0]; }
    else            { v = phi_res[(j - 8) * NCF + k];  a = alpha_res[0]; }
    phiW[idx] = (uint16_t)bf16rne(v * a * w[c]);
}

// ---------------------------------------------------------------------------
// K1: H-compute. 512 threads (8 waves), 4 rows/block. A: x -> LDS bf16 +
// sum-of-squares. B: wave w dots 4 rows vs phi rows 3w..3w+2 (dot2 ping-pong,
// scl folded at stream-segment boundaries). Sinkhorn redundant on all waves.
// Dump 24 f32/row (hp,hq,hrm) to hbuf. No output-matrix traffic.
// ---------------------------------------------------------------------------
__global__ void __launch_bounds__(512) h_kernel(
    const float* __restrict__ x,
    const uint16_t* __restrict__ phiW,
    const float* __restrict__ b_pre,
    const float* __restrict__ b_post,
    const float* __restrict__ b_res,
    float* __restrict__ hbuf)
{
    const int t = threadIdx.x;
    const int lane = t & 63;
    const int wave = t >> 6;              // 0..7
    const long b0 = (long)blockIdx.x * RPB;

    __shared__ uint32_t xn[RPB][NCF / 2]; // raw bf16 x, 4 rows, 64 KiB
    __shared__ float4 red[RPB][8];
    __shared__ float H[RPB][24] __attribute__((aligned(16)));
    __shared__ float MS[RPB][16] __attribute__((aligned(16)));

    // ---- Phase A: global -> LDS (raw bf16), sum-of-squares per stream ----
    {
        const float4* xp = reinterpret_cast<const float4*>(x + b0 * NCF);
        #pragma unroll
        for (int rp = 0; rp < RPB; rp += 2) {
            float4 a[2][4];
            #pragma unroll
            for (int rr = 0; rr < 2; ++rr)
                #pragma unroll
                for (int jj = 0; jj < 4; ++jj)
                    a[rr][jj] = xp[(rp + rr) * 2048 + t + 512 * jj];

            float ss[2][4];
            #pragma unroll
            for (int rr = 0; rr < 2; ++rr) {
                const int r = rp + rr;
                #pragma unroll
                for (int jj = 0; jj < 4; ++jj) {
                    float4 v = a[rr][jj];
                    ss[rr][jj] = v.x*v.x + v.y*v.y + v.z*v.z + v.w*v.w;
                    *reinterpret_cast<uint2*>(&xn[r][2*t + 1024*jj]) =
                        make_uint2(cvtpk(v.x, v.y), cvtpk(v.z, v.w));
                }
            }
            #pragma unroll
            for (int m = 1; m < 64; m <<= 1) {
                #pragma unroll
                for (int rr = 0; rr < 2; ++rr)
                    #pragma unroll
                    for (int jj = 0; jj < 4; ++jj)
                        ss[rr][jj] += __shfl_xor(ss[rr][jj], m, 64);
            }
            if (lane == 0) {
                red[rp][wave]     = make_float4(ss[0][0], ss[0][1], ss[0][2], ss[0][3]);
                red[rp + 1][wave] = make_float4(ss[1][0], ss[1][1], ss[1][2], ss[1][3]);
            }
        }
    }
    __syncthreads();

    // ---- SCL computed redundantly per thread (broadcast LDS reads) ----
    float scl[RPB][4];
    #pragma unroll
    for (int r = 0; r < RPB; ++r) {
        float sx = 0.f, sy = 0.f, sz = 0.f, sw = 0.f;
        #pragma unroll
        for (int w8 = 0; w8 < 8; ++w8) {
            float4 v = red[r][w8];
            sx += v.x; sy += v.y; sz += v.z; sw += v.w;
        }
        scl[r][0] = rsqrtf(sx * (1.0f / CH) + EPS_F);
        scl[r][1] = rsqrtf(sy * (1.0f / CH) + EPS_F);
        scl[r][2] = rsqrtf(sz * (1.0f / CH) + EPS_F);
        scl[r][3] = rsqrtf(sw * (1.0f / CH) + EPS_F);
    }

    // ---- Phase B: wave w dots 4 raw rows against phi rows 3w..3w+2 ----
    float accT[3][RPB] = {};
    float accS[3][RPB] = {};
    {
        const uint16_t* pw = phiW + (size_t)(wave * 3) * NCF;
        const int kl = 8 * lane;
        const uint4* xr0 = reinterpret_cast<const uint4*>(xn[0]);
        const uint4* xr1 = reinterpret_cast<const uint4*>(xn[1]);
        const uint4* xr2 = reinterpret_cast<const uint4*>(xn[2]);
        const uint4* xr3 = reinterpret_cast<const uint4*>(xn[3]);

        uint4 pA0 = *reinterpret_cast<const uint4*>(pw + 0 * NCF + kl);
        uint4 pA1 = *reinterpret_cast<const uint4*>(pw + 1 * NCF + kl);
        uint4 pA2 = *reinterpret_cast<const uint4*>(pw + 2 * NCF + kl);
        uint4 xA0 = xr0[lane], xA1 = xr1[lane], xA2 = xr2[lane], xA3 = xr3[lane];

        #pragma unroll
        for (int u = 0; u < 16; u += 2) {
            const int iB = 64 * (u + 1) + lane;
            const int kB = 512 * (u + 1) + kl;
            uint4 pB0 = *reinterpret_cast<const uint4*>(pw + 0 * NCF + kB);
            uint4 pB1 = *reinterpret_cast<const uint4*>(pw + 1 * NCF + kB);
            uint4 pB2 = *reinterpret_cast<const uint4*>(pw + 2 * NCF + kB);
            uint4 xB0 = xr0[iB], xB1 = xr1[iB], xB2 = xr2[iB], xB3 = xr3[iB];

            accS[0][0] = dot8(xA0, pA0, accS[0][0]);
            accS[0][1] = dot8(xA1, pA0, accS[0][1]);
            accS[0][2] = dot8(xA2, pA0, accS[0][2]);
            accS[0][3] = dot8(xA3, pA0, accS[0][3]);
            accS[1][0] = dot8(xA0, pA1, accS[1][0]);
            accS[1][1] = dot8(xA1, pA1, accS[1][1]);
            accS[1][2] = dot8(xA2, pA1, accS[1][2]);
            accS[1][3] = dot8(xA3, pA1, accS[1][3]);
            accS[2][0] = dot8(xA0, pA2, accS[2][0]);
            accS[2][1] = dot8(xA1, pA2, accS[2][1]);
            accS[2][2] = dot8(xA2, pA2, accS[2][2]);
            accS[2][3] = dot8(xA3, pA2, accS[2][3]);

            if (u + 2 < 16) {
                const int iA = 64 * (u + 2) + lane;
                const int kA = 512 * (u + 2) + kl;
                pA0 = *reinterpret_cast<const uint4*>(pw + 0 * NCF + kA);
                pA1 = *reinterpret_cast<const uint4*>(pw + 1 * NCF + kA);
                pA2 = *reinterpret_cast<const uint4*>(pw + 2 * NCF + kA);
                xA0 = xr0[iA]; xA1 = xr1[iA]; xA2 = xr2[iA]; xA3 = xr3[iA];
            }

            accS[0][0] = dot8(xB0, pB0, accS[0][0]);
            accS[0][1] = dot8(xB1, pB0, accS[0][1]);
            accS[0][2] = dot8(xB2, pB0, accS[0][2]);
            accS[0][3] = dot8(xB3, pB0, accS[0][3]);
            accS[1][0] = dot8(xB0, pB1, accS[1][0]);
            accS[1][1] = dot8(xB1, pB1, accS[1][1]);
            accS[1][2] = dot8(xB2, pB1, accS[1][2]);
            accS[1][3] = dot8(xB3, pB1, accS[1][3]);
            accS[2][0] = dot8(xB0, pB2, accS[2][0]);
            accS[2][1] = dot8(xB1, pB2, accS[2][1]);
            accS[2][2] = dot8(xB2, pB2, accS[2][2]);
            accS[2][3] = dot8(xB3, pB2, accS[2][3]);

            if (((u + 1) & 3) == 3) {               // end of stream segment
                const int s = (u + 1) >> 2;
                #pragma unroll
                for (int jl = 0; jl < 3; ++jl) {
                    #pragma unroll
                    for (int r = 0; r < RPB; ++r) {
                        accT[jl][r] = fmaf(scl[r][s], accS[jl][r], accT[jl][r]);
                        accS[jl][r] = 0.f;
                    }
                }
            }
        }
    }
    {
        #pragma unroll
        for (int m = 1; m < 64; m <<= 1) {
            #pragma unroll
            for (int jl = 0; jl < 3; ++jl) {
                #pragma unroll
                for (int r = 0; r < RPB; ++r)
                    accT[jl][r] += __shfl_xor(accT[jl][r], m, 64);
            }
        }
        if (lane == 0) {                 // fold bias, write H directly
            #pragma unroll
            for (int jl = 0; jl < 3; ++jl) {
                int j = 3 * wave + jl;
                float bias;
                if (j < 4)      bias = b_pre[j];
                else if (j < 8) bias = b_post[j - 4];
                else            bias = b_res[j - 8];
                #pragma unroll
                for (int r = 0; r < RPB; ++r) H[r][j] = accT[jl][r] + bias;
            }
        }
    }
    __syncthreads();

    // ---- Sinkhorn: every wave computes all 4 rows redundantly ----
    {
        const int r = lane >> 4;
        const int q = lane & 15;          // q = i*4 + jx
        float L = H[r][8 + q];
        float mx = L;
        mx = fmaxf(mx, __shfl_xor(mx, 1, 64));
        mx = fmaxf(mx, __shfl_xor(mx, 2, 64));
        mx = fmaxf(mx, __shfl_xor(mx, 4, 64));
        mx = fmaxf(mx, __shfl_xor(mx, 8, 64));
        float m = __expf(L - mx);
        #pragma unroll
        for (int it = 0; it < SINK_ITERS; ++it) {
            float rs = m + __shfl_xor(m, 1, 64);
            rs += __shfl_xor(rs, 2, 64);
            m = m * __builtin_amdgcn_rcpf(rs + EPS_F);   // row normalize
            float cs = m + __shfl_xor(m, 4, 64);
            cs += __shfl_xor(cs, 8, 64);
            m = m * __builtin_amdgcn_rcpf(cs + EPS_F);   // col normalize
        }
        MS[r][q] = m;                     // own-wave write, own-wave read below
    }

    // ---- dump h to global: 24 f32 per row (hp 0..3, hq 4..7, hrm 8..23) --
    if (t < 96) {
        const int r = t / 24;
        const int k = t - 24 * r;
        float v = (k < 8) ? H[r][k] : MS[r][k - 8];
        hbuf[(b0 + r) * 24 + k] = v;
    }
}

// ---------------------------------------------------------------------------
// K2: mixing epilogue, pure streaming. 512 threads, one row per block.
// Reads x (f32, exact) + 96 B of h; writes out with nontemporal stores.
// No LDS, no barriers.
// ---------------------------------------------------------------------------
__global__ void __launch_bounds__(512) mix_kernel(
    const float* __restrict__ x,
    const float* __restrict__ hbuf,
    float* __restrict__ out)
{
    const int t = threadIdx.x;
    const long b = blockIdx.x;

    const float4* hb = reinterpret_cast<const float4*>(hbuf + b * 24);
    const float4 hp = hb[0];
    const float4 hq = hb[1];
    const float4 h0 = hb[2], h1 = hb[3], h2 = hb[4], h3 = hb[5];

    const float4* xp = reinterpret_cast<const float4*>(x + b * NCF) + t;
    const float4 s0 = xp[0], s1 = xp[512], s2 = xp[1024], s3 = xp[1536];

    const float ax = hp.x*s0.x + hp.y*s1.x + hp.z*s2.x + hp.w*s3.x;
    const float ay = hp.x*s0.y + hp.y*s1.y + hp.z*s2.y + hp.w*s3.y;
    const float az = hp.x*s0.z + hp.y*s1.z + hp.z*s2.z + hp.w*s3.z;
    const float aw = hp.x*s0.w + hp.y*s1.w + hp.z*s2.w + hp.w*s3.w;

    v4f* op = reinterpret_cast<v4f*>(out + b * NCF) + t;
    {
        v4f o;
        o.x = h0.x*s0.x + h0.y*s1.x + h0.z*s2.x + h0.w*s3.x + hq.x*ax;
        o.y = h0.x*s0.y + h0.y*s1.y + h0.z*s2.y + h0.w*s3.y + hq.x*ay;
        o.z = h0.x*s0.z + h0.y*s1.z + h0.z*s2.z + h0.w*s3.z + hq.x*az;
        o.w = h0.x*s0.w + h0.y*s1.w + h0.z*s2.w + h0.w*s3.w + hq.x*aw;
        __builtin_nontemporal_store(o, op);
    }
    {
        v4f o;
        o.x = h1.x*s0.x + h1.y*s1.x + h1.z*s2.x + h1.w*s3.x + hq.y*ax;
        o.y = h1.x*s0.y + h1.y*s1.y + h1.z*s2.y + h1.w*s3.y + hq.y*ay;
        o.z = h1.x*s0.z + h1.y*s1.z + h1.z*s2.z + h1.w*s3.z + hq.y*az;
        o.w = h1.x*s0.w + h1.y*s1.w + h1.z*s2.w + h1.w*s3.w + hq.y*aw;
        __builtin_nontemporal_store(o, op + 512);
    }
    {
        v4f o;
        o.x = h2.x*s0.x + h2.y*s1.x + h2.z*s2.x + h2.w*s3.x + hq.z*ax;
        o.y = h2.x*s0.y + h2.y*s1.y + h2.z*s2.y + h2.w*s3.y + hq.z*ay;
        o.z = h2.x*s0.z + h2.y*s1.z + h2.z*s2.z + h2.w*s3.z + hq.z*az;
        o.w = h2.x*s0.w + h2.y*s1.w + h2.z*s2.w + h2.w*s3.w + hq.z*aw;
        __builtin_nontemporal_store(o, op + 1024);
    }
    {
        v4f o;
        o.x = h3.x*s0.x + h3.y*s1.x + h3.z*s2.x + h3.w*s3.x + hq.w*ax;
        o.y = h3.x*s0.y + h3.y*s1.y + h3.z*s2.y + h3.w*s3.y + hq.w*ay;
        o.z = h3.x*s0.z + h3.y*s1.z + h3.z*s2.z + h3.w*s3.z + hq.w*az;
        o.w = h3.x*s0.w + h3.y*s1.w + h3.z*s2.w + h3.w*s3.w + hq.w*aw;
        __builtin_nontemporal_store(o, op + 1536);
    }
}

extern "C" void kernel_launch(void* const* d_in, const int* in_sizes, int n_in,
                              void* d_out, int out_size, void* d_ws, size_t ws_size,
                              hipStream_t stream)
{
    const float* x        = (const float*)d_in[0];
    const float* w        = (const float*)d_in[1];
    const float* phi_pre  = (const float*)d_in[2];
    const float* phi_post = (const float*)d_in[3];
    const float* phi_res  = (const float*)d_in[4];
    const float* b_pre    = (const float*)d_in[5];
    const float* b_post   = (const float*)d_in[6];
    const float* b_res    = (const float*)d_in[7];
    const float* a_pre    = (const float*)d_in[8];
    const float* a_post   = (const float*)d_in[9];
    const float* a_res    = (const float*)d_in[10];
    float* out = (float*)d_out;

    uint16_t* phiW = (uint16_t*)d_ws;                    // 384 KiB
    float* hbuf = (float*)((char*)d_ws + (size_t)NJ * NCF * 2);  // 8192*24*4 = 768 KiB

    const int B = in_sizes[0] / NCF;    // 8192

    prep_phi_kernel<<<(NJ * NCF + 255) / 256, 256, 0, stream>>>(
        w, phi_pre, phi_post, phi_res, a_pre, a_post, a_res, phiW);

    h_kernel<<<B / RPB, 512, 0, stream>>>(
        x, phiW, b_pre, b_post, b_res, hbuf);

    mix_kernel<<<B, 512, 0, stream>>>(x, hbuf, out);
}